// Round 1
// baseline (970.361 us; speedup 1.0000x reference)
//
#include <hip/hip_runtime.h>

// DPP helpers: rotate within 16-lane rows. CTRL = 0x120 + r  (row_ror:r)
#define ROTI(v, CTRL) __builtin_amdgcn_update_dpp(0, (v), (CTRL), 0xF, 0xF, true)
#define ROTF(x, CTRL) __int_as_float(__builtin_amdgcn_update_dpp(0, __float_as_int(x), (CTRL), 0xF, 0xF, true))

constexpr int T_LEN = 8192;
constexpr int BATCH = 256;
constexpr int HID   = 16;

__global__ void __launch_bounds__(64, 1)
rnn_fused(const float* __restrict__ x,
          const float* __restrict__ h0,
          const float* __restrict__ Wih,
          const float* __restrict__ Whh,
          const float* __restrict__ bih,
          const float* __restrict__ bhh,
          const float* __restrict__ Wout,
          const float* __restrict__ boutp,
          float* __restrict__ out)
{
    const int lane = (int)threadIdx.x;   // 0..63
    const int j    = lane & 15;          // hidden index this lane owns
    const int b    = (int)blockIdx.x * 4 + (lane >> 4);  // batch element

    // Probe DPP row_ror direction: after ror:1, what does lane 0 receive?
    // If it receives lane 1's value -> arriving value at rotation r is h[(j+r)&15].
    const int pr  = ROTI(j, 0x121);
    const int dir = (__builtin_amdgcn_readfirstlane(pr) == 1) ? 1 : -1;

    // Pre-rotated W_hh row for this lane: term r multiplies h[(j + dir*r)&15]
    float wr[16];
#pragma unroll
    for (int r = 0; r < 16; ++r)
        wr[r] = Whh[j * HID + ((j + dir * r) & 15)];

    const float wih  = Wih[j];           // W_ih[j][0], I==1
    const float bias = bih[j] + bhh[j];
    const float wout = Wout[j];          // W_out[0][j], O==1
    const float bo   = boutp[0];

    float h = h0[b * HID + j];

    const float* xb = x  + (size_t)b * T_LEN;       // x[b][t], contiguous in t
    float*       ob = out + (size_t)b * T_LEN;      // out[b*T + t]
    float*       hT = out + (size_t)BATCH * T_LEN;  // hidden state after outs

    auto step = [&](float xv) -> float {
        // 15 rotations of h, all independent (latency ~1 DPP mov after h ready)
        float r1  = ROTF(h, 0x121), r2  = ROTF(h, 0x122), r3  = ROTF(h, 0x123);
        float r4  = ROTF(h, 0x124), r5  = ROTF(h, 0x125), r6  = ROTF(h, 0x126);
        float r7  = ROTF(h, 0x127), r8  = ROTF(h, 0x128), r9  = ROTF(h, 0x129);
        float r10 = ROTF(h, 0x12A), r11 = ROTF(h, 0x12B), r12 = ROTF(h, 0x12C);
        float r13 = ROTF(h, 0x12D), r14 = ROTF(h, 0x12E), r15 = ROTF(h, 0x12F);

        // dot(h, W_hh[j][:]) + xp, 4 independent accumulator chains
        float a0 = fmaf(xv, wih, bias);      // xp_t[j] = x_t*W_ih[j] + b_ih + b_hh
        a0 = fmaf(h,   wr[0], a0);
        a0 = fmaf(r1,  wr[1], a0);
        a0 = fmaf(r2,  wr[2], a0);
        a0 = fmaf(r3,  wr[3], a0);
        float a1 = r4 * wr[4];
        a1 = fmaf(r5,  wr[5],  a1);
        a1 = fmaf(r6,  wr[6],  a1);
        a1 = fmaf(r7,  wr[7],  a1);
        float a2 = r8 * wr[8];
        a2 = fmaf(r9,  wr[9],  a2);
        a2 = fmaf(r10, wr[10], a2);
        a2 = fmaf(r11, wr[11], a2);
        float a3 = r12 * wr[12];
        a3 = fmaf(r13, wr[13], a3);
        a3 = fmaf(r14, wr[14], a3);
        a3 = fmaf(r15, wr[15], a3);
        float s = (a0 + a1) + (a2 + a3);

        // tanh(s) = 1 - 2/(1 + e^{2s});  saturates correctly: e=inf -> 1, e=0 -> -1
        float e  = __expf(s + s);
        float hn = fmaf(-2.0f, __builtin_amdgcn_rcpf(e + 1.0f), 1.0f);
        h = hn;

        // out_t = sum_j hn[j]*W_out[j] + b_out  — rotation allreduce over the row
        float p = hn * wout;
        p += ROTF(p, 0x128);
        p += ROTF(p, 0x124);
        p += ROTF(p, 0x122);
        p += ROTF(p, 0x121);
        return p + bo;
    };

    float4 xq = *(const float4*)xb;          // x[t..t+3]
    const bool writer = (j == 0);

    for (int t = 0; t < T_LEN; t += 4) {
        const int tn = (t + 4) & (T_LEN - 1);        // wraps to 0 on last iter (safe dummy)
        float4 xn = *(const float4*)(xb + tn);       // prefetch next 4 inputs

        float o0 = step(xq.x);
        float o1 = step(xq.y);
        float o2 = step(xq.z);
        float o3 = step(xq.w);

        if (writer)
            *(float4*)(ob + t) = make_float4(o0, o1, o2, o3);
        xq = xn;
    }

    hT[(size_t)b * HID + j] = h;   // final hidden state [1,B,H]
}

extern "C" void kernel_launch(void* const* d_in, const int* in_sizes, int n_in,
                              void* d_out, int out_size, void* d_ws, size_t ws_size,
                              hipStream_t stream)
{
    const float* x    = (const float*)d_in[0];
    const float* h0   = (const float*)d_in[1];
    const float* Wih  = (const float*)d_in[2];
    const float* Whh  = (const float*)d_in[3];
    const float* bih  = (const float*)d_in[4];
    const float* bhh  = (const float*)d_in[5];
    const float* Wout = (const float*)d_in[6];
    const float* bout = (const float*)d_in[7];
    float* out = (float*)d_out;

    rnn_fused<<<dim3(BATCH / 4), dim3(64), 0, stream>>>(
        x, h0, Wih, Whh, bih, bhh, Wout, bout, out);
}

// Round 2
// 599.018 us; speedup vs baseline: 1.6199x; 1.6199x over previous
//
#include <hip/hip_runtime.h>

// DPP helpers (builtin path, used for direction probe + final reduce only)
#define ROTI(v, CTRL) __builtin_amdgcn_update_dpp(0, (v), (CTRL), 0xF, 0xF, true)
#define ROTF(x, CTRL) __int_as_float(__builtin_amdgcn_update_dpp(0, __float_as_int(x), (CTRL), 0xF, 0xF, true))

constexpr int T_LEN = 8192;
constexpr int BATCH = 256;
constexpr int HID   = 16;

// One fused step-core: 16x16 matvec of h against pre-rotated weight rows
// (v_fmac_f32_dpp / v_mul_f32_dpp, DPP on src0) with the PREVIOUS step's
// output-projection reduce (v_add_f32_dpp p,p,p tree) interleaved.
// Hazard discipline (compiler can't see DPP inside asm):
//   - s_nop 1 at head guards h/p written by compiler code just before the block
//   - every VGPR write is >=3 instructions before any DPP read of it
// Chains a0..a3 are touched every 4-5 insts (~8-10 cy) > ~5 cy VALU latency.
#define MATVEC(a0_, a1_, a2_, a3_, p_, h_)                                              \
  asm("s_nop 1\n\t"                                                                     \
      "v_fmac_f32 %[a0], %[h], %[w0]\n\t"                                               \
      "v_mul_f32_dpp %[a1], %[h], %[w4] row_ror:4 row_mask:0xf bank_mask:0xf\n\t"       \
      "v_mul_f32_dpp %[a2], %[h], %[w8] row_ror:8 row_mask:0xf bank_mask:0xf\n\t"       \
      "v_mul_f32_dpp %[a3], %[h], %[w12] row_ror:12 row_mask:0xf bank_mask:0xf\n\t"     \
      "v_add_f32_dpp %[p], %[p], %[p] row_ror:8 row_mask:0xf bank_mask:0xf\n\t"         \
      "v_fmac_f32_dpp %[a0], %[h], %[w1] row_ror:1 row_mask:0xf bank_mask:0xf\n\t"      \
      "v_fmac_f32_dpp %[a1], %[h], %[w5] row_ror:5 row_mask:0xf bank_mask:0xf\n\t"      \
      "v_fmac_f32_dpp %[a2], %[h], %[w9] row_ror:9 row_mask:0xf bank_mask:0xf\n\t"      \
      "v_add_f32_dpp %[p], %[p], %[p] row_ror:4 row_mask:0xf bank_mask:0xf\n\t"         \
      "v_fmac_f32_dpp %[a3], %[h], %[w13] row_ror:13 row_mask:0xf bank_mask:0xf\n\t"    \
      "v_fmac_f32_dpp %[a0], %[h], %[w2] row_ror:2 row_mask:0xf bank_mask:0xf\n\t"      \
      "v_fmac_f32_dpp %[a1], %[h], %[w6] row_ror:6 row_mask:0xf bank_mask:0xf\n\t"      \
      "v_add_f32_dpp %[p], %[p], %[p] row_ror:2 row_mask:0xf bank_mask:0xf\n\t"         \
      "v_fmac_f32_dpp %[a2], %[h], %[w10] row_ror:10 row_mask:0xf bank_mask:0xf\n\t"    \
      "v_fmac_f32_dpp %[a3], %[h], %[w14] row_ror:14 row_mask:0xf bank_mask:0xf\n\t"    \
      "v_fmac_f32_dpp %[a0], %[h], %[w3] row_ror:3 row_mask:0xf bank_mask:0xf\n\t"      \
      "v_add_f32_dpp %[p], %[p], %[p] row_ror:1 row_mask:0xf bank_mask:0xf\n\t"         \
      "v_fmac_f32_dpp %[a1], %[h], %[w7] row_ror:7 row_mask:0xf bank_mask:0xf\n\t"      \
      "v_fmac_f32_dpp %[a2], %[h], %[w11] row_ror:11 row_mask:0xf bank_mask:0xf\n\t"    \
      "v_fmac_f32_dpp %[a3], %[h], %[w15] row_ror:15 row_mask:0xf bank_mask:0xf\n\t"    \
      : [a0]"+v"(a0_), [a1]"=&v"(a1_), [a2]"=&v"(a2_), [a3]"=&v"(a3_), [p]"+v"(p_)     \
      : [h]"v"(h_),                                                                     \
        [w0]"v"(wr[0]),  [w1]"v"(wr[1]),  [w2]"v"(wr[2]),  [w3]"v"(wr[3]),              \
        [w4]"v"(wr[4]),  [w5]"v"(wr[5]),  [w6]"v"(wr[6]),  [w7]"v"(wr[7]),              \
        [w8]"v"(wr[8]),  [w9]"v"(wr[9]),  [w10]"v"(wr[10]), [w11]"v"(wr[11]),           \
        [w12]"v"(wr[12]), [w13]"v"(wr[13]), [w14]"v"(wr[14]), [w15]"v"(wr[15]))

// One RNN step. On entry p holds (elementwise) h_prev * wout; the asm block
// reduces it to the row-sum => o = out_{t-1}. LSEL = (global_step + 15) & 15:
// lane LSEL keeps o so that after 16 steps lane j holds out[t_base + j].
#define STEP(XV, LSEL) do {                                                             \
    float a0 = fmaf((XV), wih, bias), a1, a2, a3;                                       \
    MATVEC(a0, a1, a2, a3, p, h);                                                       \
    float o = p + bo;                                                                   \
    osel = (j == (LSEL)) ? o : osel;                                                    \
    float s = (a0 + a1) + (a2 + a3);                                                    \
    float e = __expf(s + s);                                                            \
    h = fmaf(-2.0f, __builtin_amdgcn_rcpf(e + 1.0f), 1.0f);                             \
    p = h * wout;                                                                       \
} while (0)

__global__ void __launch_bounds__(64, 1)
rnn_fused(const float* __restrict__ x,
          const float* __restrict__ h0,
          const float* __restrict__ Wih,
          const float* __restrict__ Whh,
          const float* __restrict__ bih,
          const float* __restrict__ bhh,
          const float* __restrict__ Wout,
          const float* __restrict__ boutp,
          float* __restrict__ out)
{
    const int lane = (int)threadIdx.x;               // 0..63
    const int j    = lane & 15;                      // hidden index this lane owns
    const int b    = (int)blockIdx.x * 4 + (lane >> 4);

    // Probe DPP row_ror direction (same as round 1, passed): arriving value at
    // rotation r is h[(j + dir*r) & 15].
    const int pr  = ROTI(j, 0x121);
    const int dir = (__builtin_amdgcn_readfirstlane(pr) == 1) ? 1 : -1;

    float wr[16];
#pragma unroll
    for (int r = 0; r < 16; ++r)
        wr[r] = Whh[j * HID + ((j + dir * r) & 15)];

    const float wih  = Wih[j];
    const float bias = bih[j] + bhh[j];
    const float wout = Wout[j];
    const float bo   = boutp[0];

    float h = h0[b * HID + j];
    float p = h * wout;          // elementwise; reduced inside first step's asm
    float osel = 0.0f;

    const float* xb = x   + (size_t)b * T_LEN;
    float*       ob = out + (size_t)b * T_LEN;

    const float4* xv4 = (const float4*)xb;
    float4 c0 = xv4[0], c1 = xv4[1], c2 = xv4[2], c3 = xv4[3];

    for (int t = 0; t < T_LEN; t += 16) {
        // prefetch next 16 x values (distance ~1400 cy >> HBM latency)
        const float4* nx = (const float4*)(xb + ((t + 16) & (T_LEN - 1)));
        float4 n0 = nx[0], n1 = nx[1], n2 = nx[2], n3 = nx[3];

        STEP(c0.x, 15);                       // produces out_{t-1} -> lane 15
        if (t > 0)                            // wave-uniform branch
            ob[t - 16 + j] = osel;            // coalesced store of out[t-16..t-1]
        STEP(c0.y, 0);
        STEP(c0.z, 1);
        STEP(c0.w, 2);
        STEP(c1.x, 3);
        STEP(c1.y, 4);
        STEP(c1.z, 5);
        STEP(c1.w, 6);
        STEP(c2.x, 7);
        STEP(c2.y, 8);
        STEP(c2.z, 9);
        STEP(c2.w, 10);
        STEP(c3.x, 11);
        STEP(c3.y, 12);
        STEP(c3.z, 13);
        STEP(c3.w, 14);

        c0 = n0; c1 = n1; c2 = n2; c3 = n3;
    }

    // Final output out[T-1]: reduce the last p (builtin DPP; compiler handles
    // its own hazards here).
    p += ROTF(p, 0x128);
    p += ROTF(p, 0x124);
    p += ROTF(p, 0x122);
    p += ROTF(p, 0x121);
    float o_last = p + bo;
    osel = (j == 15) ? o_last : osel;
    ob[T_LEN - 16 + j] = osel;               // out[T-16..T-1]

    out[(size_t)BATCH * T_LEN + (size_t)b * HID + j] = h;   // hT [1,B,H]
}

extern "C" void kernel_launch(void* const* d_in, const int* in_sizes, int n_in,
                              void* d_out, int out_size, void* d_ws, size_t ws_size,
                              hipStream_t stream)
{
    const float* x    = (const float*)d_in[0];
    const float* h0   = (const float*)d_in[1];
    const float* Wih  = (const float*)d_in[2];
    const float* Whh  = (const float*)d_in[3];
    const float* bih  = (const float*)d_in[4];
    const float* bhh  = (const float*)d_in[5];
    const float* Wout = (const float*)d_in[6];
    const float* bout = (const float*)d_in[7];
    float* out = (float*)d_out;

    rnn_fused<<<dim3(BATCH / 4), dim3(64), 0, stream>>>(
        x, h0, Wih, Whh, bih, bhh, Wout, bout, out);
}